// Round 1
// baseline (35.417 us; speedup 1.0000x reference)
//
#include <hip/hip_runtime.h>
#include <math.h>

// NeRF loss: d_rgb = (rgb-target)^2 ; d_opacity = L_op * (-o log o) ;
// d_distortion = L_dist * per-ray distortion loss (wave-local scan, exact).

#define LAMBDA_OPACITY 0.001f
#define LAMBDA_DISTORTION 0.001f

__global__ void elemwise_kernel(const float* __restrict__ rgb,
                                const float* __restrict__ target_rgb,
                                const float* __restrict__ opacity,
                                float* __restrict__ out_rgb,
                                float* __restrict__ out_op,
                                int n_rgb, int n_rays) {
    int i = blockIdx.x * blockDim.x + threadIdx.x;
    if (i < n_rgb) {
        float d = rgb[i] - target_rgb[i];
        out_rgb[i] = d * d;
    }
    if (i < n_rays) {
        float o = opacity[i] + 1e-10f;
        out_op[i] = LAMBDA_OPACITY * (-o * logf(o));
    }
}

// One 64-lane wave per ray. Inclusive scan of (w, w*t) via shfl_up,
// carry across 64-sample chunks, wave-reduce the per-sample loss.
__global__ void distortion_kernel(const float* __restrict__ ws,
                                  const float* __restrict__ deltas,
                                  const float* __restrict__ ts,
                                  const int* __restrict__ rays_a,
                                  float* __restrict__ out,
                                  int n_rays) {
    const int wave = threadIdx.x >> 6;
    const int lane = threadIdx.x & 63;
    const int ray = blockIdx.x * (blockDim.x >> 6) + wave;
    if (ray >= n_rays) return;

    const int out_idx = rays_a[ray * 3 + 0];
    const int start   = rays_a[ray * 3 + 1];
    const int count   = rays_a[ray * 3 + 2];

    float carry_w = 0.f, carry_wt = 0.f, acc = 0.f;

    for (int base = 0; base < count; base += 64) {
        const int i = base + lane;
        const bool valid = (i < count);
        float w = 0.f, t = 0.f, d = 0.f;
        if (valid) {
            w = ws[start + i];
            t = ts[start + i];
            d = deltas[start + i];
        }
        const float wt = w * t;

        float sw = w, swt = wt;
        #pragma unroll
        for (int off = 1; off < 64; off <<= 1) {
            float pw  = __shfl_up(sw,  off);
            float pwt = __shfl_up(swt, off);
            if (lane >= off) { sw += pw; swt += pwt; }
        }
        const float W_incl  = sw  + carry_w;
        const float WT_incl = swt + carry_wt;

        if (valid) {
            // 2*w*(t*(W_incl - w) - (WT_incl - w*t)) + w*w*d/3
            acc += 2.f * w * (t * (W_incl - w) - (WT_incl - wt))
                 + w * w * d * (1.f / 3.f);
        }
        carry_w  += __shfl(sw,  63);
        carry_wt += __shfl(swt, 63);
    }

    // wave reduction of acc
    #pragma unroll
    for (int off = 32; off > 0; off >>= 1)
        acc += __shfl_down(acc, off);

    if (lane == 0)
        out[out_idx] = LAMBDA_DISTORTION * acc;
}

extern "C" void kernel_launch(void* const* d_in, const int* in_sizes, int n_in,
                              void* d_out, int out_size, void* d_ws, size_t ws_size,
                              hipStream_t stream) {
    const float* rgb        = (const float*)d_in[0];
    const float* target_rgb = (const float*)d_in[1];
    const float* opacity    = (const float*)d_in[2];
    const float* ws         = (const float*)d_in[3];
    const float* deltas     = (const float*)d_in[4];
    const float* ts         = (const float*)d_in[5];
    const int*   rays_a     = (const int*)d_in[6];

    const int n_rgb  = in_sizes[0];   // N_RAYS * 3
    const int n_rays = in_sizes[2];   // N_RAYS

    float* out      = (float*)d_out;
    float* out_rgb  = out;
    float* out_op   = out + n_rgb;
    float* out_dist = out + n_rgb + n_rays;

    {
        const int threads = 256;
        const int blocks = (n_rgb + threads - 1) / threads;
        elemwise_kernel<<<blocks, threads, 0, stream>>>(
            rgb, target_rgb, opacity, out_rgb, out_op, n_rgb, n_rays);
    }
    {
        const int waves_per_block = 4;
        const int threads = waves_per_block * 64;
        const int blocks = (n_rays + waves_per_block - 1) / waves_per_block;
        distortion_kernel<<<blocks, threads, 0, stream>>>(
            ws, deltas, ts, rays_a, out_dist, n_rays);
    }
}

// Round 2
// 26.281 us; speedup vs baseline: 1.3477x; 1.3477x over previous
//
#include <hip/hip_runtime.h>
#include <math.h>

#define LAMBDA_OPACITY 0.001f
#define LAMBDA_DISTORTION 0.001f

// Fused NeRF loss kernel.
// Each block: 4 waves x 1 ray distortion (pair-per-lane, single scan)
//           + a 16-element slice of the rgb/opacity elementwise outputs.
//
// Distortion identity: loss = 2*sum_{j<i} w_i w_j (t_i - t_j) + sum w^2 d /3.
// Lane l owns samples (2l, 2l+1): local Lw, Lwt; one exclusive scan across
// lanes gives Pw, Pwt; lane loss = 2(Lwt*Pw - Lw*Pwt) + 2 w0 w1 (t1-t0)
// + (w0^2 d0 + w1^2 d1)/3. Wave-reduce, lane 0 writes.
__global__ void __launch_bounds__(256) fused_nerf_loss(
        const float* __restrict__ rgb,
        const float* __restrict__ target_rgb,
        const float* __restrict__ opacity,
        const float* __restrict__ ws,
        const float* __restrict__ deltas,
        const float* __restrict__ ts,
        const int* __restrict__ rays_a,
        float* __restrict__ out_rgb,
        float* __restrict__ out_op,
        float* __restrict__ out_dist,
        int n_rgb, int n_rays) {
    const int tid = threadIdx.x;
    const int wave = tid >> 6;
    const int lane = tid & 63;

    // ---- elementwise slice: 16 consecutive elements per block ----
    if (tid < 16) {
        int e = blockIdx.x * 16 + tid;
        if (e < n_rgb) {
            float d = rgb[e] - target_rgb[e];
            out_rgb[e] = d * d;
        } else {
            int oi = e - n_rgb;
            if (oi < n_rays) {
                float o = opacity[oi] + 1e-10f;
                out_op[oi] = LAMBDA_OPACITY * (-o * logf(o));
            }
        }
    }

    // ---- distortion: one ray per wave ----
    const int ray = blockIdx.x * 4 + wave;
    if (ray >= n_rays) return;

    const int out_idx = rays_a[ray * 3 + 0];
    const int start   = rays_a[ray * 3 + 1];
    const int count   = rays_a[ray * 3 + 2];

    float acc = 0.f, carry_w = 0.f, carry_wt = 0.f;

    for (int base = 0; base < count; base += 128) {
        const int i0 = base + 2 * lane;
        float2 wv = make_float2(0.f, 0.f);
        float2 tv = make_float2(0.f, 0.f);
        float2 dv = make_float2(0.f, 0.f);
        if (i0 + 1 < count) {
            wv = *reinterpret_cast<const float2*>(ws     + start + i0);
            tv = *reinterpret_cast<const float2*>(ts     + start + i0);
            dv = *reinterpret_cast<const float2*>(deltas + start + i0);
        } else if (i0 < count) {
            wv.x = ws[start + i0];
            tv.x = ts[start + i0];
            dv.x = deltas[start + i0];
        }

        const float Lw  = wv.x + wv.y;
        const float Lwt = wv.x * tv.x + wv.y * tv.y;

        // inclusive scan across 64 lanes (6 steps, 2 values)
        float sw = Lw, swt = Lwt;
        #pragma unroll
        for (int off = 1; off < 64; off <<= 1) {
            float pw  = __shfl_up(sw,  off);
            float pwt = __shfl_up(swt, off);
            if (lane >= off) { sw += pw; swt += pwt; }
        }
        const float Pw  = sw  - Lw  + carry_w;   // exclusive prefix
        const float Pwt = swt - Lwt + carry_wt;

        acc += 2.f * (Lwt * Pw - Lw * Pwt)
             + 2.f * wv.x * wv.y * (tv.y - tv.x)
             + (wv.x * wv.x * dv.x + wv.y * wv.y * dv.y) * (1.f / 3.f);

        if (base + 128 < count) {   // carry only if another chunk follows
            carry_w  += __shfl(sw,  63);
            carry_wt += __shfl(swt, 63);
        }
    }

    // butterfly reduce across the wave
    #pragma unroll
    for (int off = 1; off < 64; off <<= 1)
        acc += __shfl_xor(acc, off);

    if (lane == 0)
        out_dist[out_idx] = LAMBDA_DISTORTION * acc;
}

extern "C" void kernel_launch(void* const* d_in, const int* in_sizes, int n_in,
                              void* d_out, int out_size, void* d_ws, size_t ws_size,
                              hipStream_t stream) {
    const float* rgb        = (const float*)d_in[0];
    const float* target_rgb = (const float*)d_in[1];
    const float* opacity    = (const float*)d_in[2];
    const float* ws         = (const float*)d_in[3];
    const float* deltas     = (const float*)d_in[4];
    const float* ts         = (const float*)d_in[5];
    const int*   rays_a     = (const int*)d_in[6];

    const int n_rgb  = in_sizes[0];   // N_RAYS * 3
    const int n_rays = in_sizes[2];   // N_RAYS

    float* out      = (float*)d_out;
    float* out_rgb  = out;
    float* out_op   = out + n_rgb;
    float* out_dist = out + n_rgb + n_rays;

    const int blocks = (n_rays + 3) / 4;   // 4 rays per block
    fused_nerf_loss<<<blocks, 256, 0, stream>>>(
        rgb, target_rgb, opacity, ws, deltas, ts, rays_a,
        out_rgb, out_op, out_dist, n_rgb, n_rays);
}

// Round 3
// 21.122 us; speedup vs baseline: 1.6768x; 1.2442x over previous
//
#include <hip/hip_runtime.h>
#include <math.h>

#define LAMBDA_OPACITY 0.001f
#define LAMBDA_DISTORTION 0.001f

// Fused NeRF loss.
// Distortion: loss = 2*sum_{j<i} w_i w_j (t_i - t_j) + sum w^2 d / 3.
// 16 lanes per ray, 8 consecutive samples per lane (2x float4 loads).
// Lane-local sequential prefix (VALU), one 4-step cross-lane scan of
// (sum w, sum w*t) within each 16-lane group, 4-step butterfly reduce.
// 4 rays per wave, 16 rays per 256-thread block.
__global__ void __launch_bounds__(256) fused_nerf_loss(
        const float* __restrict__ rgb,
        const float* __restrict__ target_rgb,
        const float* __restrict__ opacity,
        const float* __restrict__ ws,
        const float* __restrict__ deltas,
        const float* __restrict__ ts,
        const int* __restrict__ rays_a,
        float* __restrict__ out_rgb,
        float* __restrict__ out_op,
        float* __restrict__ out_dist,
        int n_rgb, int n_rays) {
    const int tid = threadIdx.x;

    // ---- elementwise: 16 float4 chunks per block (regions are %4==0) ----
    if (tid < 16) {
        const int e = (blockIdx.x * 16 + tid) * 4;
        if (e < n_rgb) {
            float4 a = *reinterpret_cast<const float4*>(rgb + e);
            float4 b = *reinterpret_cast<const float4*>(target_rgb + e);
            float4 r;
            r.x = (a.x - b.x) * (a.x - b.x);
            r.y = (a.y - b.y) * (a.y - b.y);
            r.z = (a.z - b.z) * (a.z - b.z);
            r.w = (a.w - b.w) * (a.w - b.w);
            *reinterpret_cast<float4*>(out_rgb + e) = r;
        } else if (e < n_rgb + n_rays) {
            const int oi = e - n_rgb;
            float4 o = *reinterpret_cast<const float4*>(opacity + oi);
            float4 r;
            float ox = o.x + 1e-10f, oy = o.y + 1e-10f;
            float oz = o.z + 1e-10f, ow = o.w + 1e-10f;
            r.x = LAMBDA_OPACITY * (-ox * logf(ox));
            r.y = LAMBDA_OPACITY * (-oy * logf(oy));
            r.z = LAMBDA_OPACITY * (-oz * logf(oz));
            r.w = LAMBDA_OPACITY * (-ow * logf(ow));
            *reinterpret_cast<float4*>(out_op + oi) = r;
        }
    }

    // ---- distortion ----
    const int wave = tid >> 6;
    const int lane = tid & 63;
    const int sub  = lane & 15;   // lane within the ray's 16-lane group
    const int grp  = lane >> 4;   // which of 4 rays this wave handles
    const int ray  = blockIdx.x * 16 + wave * 4 + grp;
    if (ray >= n_rays) return;

    const int out_idx = rays_a[ray * 3 + 0];
    const int start   = rays_a[ray * 3 + 1];
    const int count   = rays_a[ray * 3 + 2];

    float acc = 0.f, carry_w = 0.f, carry_wt = 0.f;

    for (int base = 0; base < count; base += 128) {
        const int i0 = base + sub * 8;
        float w[8], t[8], dl[8];
        if (i0 + 8 <= count) {
            const float4 w0 = *reinterpret_cast<const float4*>(ws     + start + i0);
            const float4 w1 = *reinterpret_cast<const float4*>(ws     + start + i0 + 4);
            const float4 t0 = *reinterpret_cast<const float4*>(ts     + start + i0);
            const float4 t1 = *reinterpret_cast<const float4*>(ts     + start + i0 + 4);
            const float4 d0 = *reinterpret_cast<const float4*>(deltas + start + i0);
            const float4 d1 = *reinterpret_cast<const float4*>(deltas + start + i0 + 4);
            w[0]=w0.x; w[1]=w0.y; w[2]=w0.z; w[3]=w0.w;
            w[4]=w1.x; w[5]=w1.y; w[6]=w1.z; w[7]=w1.w;
            t[0]=t0.x; t[1]=t0.y; t[2]=t0.z; t[3]=t0.w;
            t[4]=t1.x; t[5]=t1.y; t[6]=t1.z; t[7]=t1.w;
            dl[0]=d0.x; dl[1]=d0.y; dl[2]=d0.z; dl[3]=d0.w;
            dl[4]=d1.x; dl[5]=d1.y; dl[6]=d1.z; dl[7]=d1.w;
        } else {
            #pragma unroll
            for (int k = 0; k < 8; ++k) {
                const int i = i0 + k;
                const bool v = (i < count);
                w[k]  = v ? ws[start + i]     : 0.f;
                t[k]  = v ? ts[start + i]     : 0.f;
                dl[k] = v ? deltas[start + i] : 0.f;
            }
        }

        // lane-local sequential prefix over 8 samples
        float lw = 0.f, lwt = 0.f, cpair = 0.f, csq = 0.f;
        #pragma unroll
        for (int k = 0; k < 8; ++k) {
            const float wk = w[k], tk = t[k];
            cpair += wk * (tk * lw - lwt);
            csq   += wk * wk * dl[k];
            lw  += wk;
            lwt += wk * tk;
        }

        // inclusive scan of (lw, lwt) within the 16-lane group
        float sw = lw, swt = lwt;
        #pragma unroll
        for (int off = 1; off < 16; off <<= 1) {
            const float pw  = __shfl_up(sw,  off, 16);
            const float pwt = __shfl_up(swt, off, 16);
            if (sub >= off) { sw += pw; swt += pwt; }
        }
        const float Pw  = sw  - lw  + carry_w;   // exclusive prefix
        const float Pwt = swt - lwt + carry_wt;

        acc += 2.f * (cpair + lwt * Pw - lw * Pwt) + csq * (1.f / 3.f);

        if (base + 128 < count) {
            carry_w  += __shfl(sw,  15, 16);
            carry_wt += __shfl(swt, 15, 16);
        }
    }

    // butterfly reduce within the 16-lane group
    #pragma unroll
    for (int off = 1; off < 16; off <<= 1)
        acc += __shfl_xor(acc, off, 16);

    if (sub == 0)
        out_dist[out_idx] = LAMBDA_DISTORTION * acc;
}

extern "C" void kernel_launch(void* const* d_in, const int* in_sizes, int n_in,
                              void* d_out, int out_size, void* d_ws, size_t ws_size,
                              hipStream_t stream) {
    const float* rgb        = (const float*)d_in[0];
    const float* target_rgb = (const float*)d_in[1];
    const float* opacity    = (const float*)d_in[2];
    const float* ws         = (const float*)d_in[3];
    const float* deltas     = (const float*)d_in[4];
    const float* ts         = (const float*)d_in[5];
    const int*   rays_a     = (const int*)d_in[6];

    const int n_rgb  = in_sizes[0];   // N_RAYS * 3
    const int n_rays = in_sizes[2];   // N_RAYS

    float* out      = (float*)d_out;
    float* out_rgb  = out;
    float* out_op   = out + n_rgb;
    float* out_dist = out + n_rgb + n_rays;

    const int blocks = (n_rays + 15) / 16;   // 16 rays per block
    fused_nerf_loss<<<blocks, 256, 0, stream>>>(
        rgb, target_rgb, opacity, ws, deltas, ts, rays_a,
        out_rgb, out_op, out_dist, n_rgb, n_rays);
}